// Round 2
// baseline (1619.259 us; speedup 1.0000x reference)
//
#include <hip/hip_runtime.h>
#include <math.h>

#define B_   512
#define T_   500
#define C_   3
#define D_   40
#define CD_  120
#define N_   256
#define OUT_ 12
#define G_   16          // batch rows per block -> 32 blocks

typedef __attribute__((ext_vector_type(8))) short short8;   // 8 x bf16 (4 VGPRs)
typedef __attribute__((ext_vector_type(4))) float f32x4;    // MFMA accumulator

// ws (ushort units): bf16 B-fragment tables.
// Frag layout (verified mapping): B[k][n], n = nt*16+(lane&15), k = kt*32+(lane>>4)*8+j
// element index = ((kt*16+nt)*64 + lane)*8 + j
#define W2IN_F  0        // kt<8, nt<16  -> 65536
#define W2REC_F 65536    // kt<8, nt<16  -> 65536
#define W1_F    131072   // kt<4, nt<16  -> 32768 (k>=120 zero)
#define W3_F    163840   // kt<8, single nt (cols=OUT pad 16) -> 4096

__device__ __forceinline__ unsigned short f2bf(float v) {
    unsigned x = __float_as_uint(v);
    unsigned r = (x + 0x7fffu + ((x >> 16) & 1u)) >> 16;   // round-nearest-even
    return (unsigned short)r;
}

// ---------------- prep: build bf16 B-fragment tables in ws ----------------
__global__ void prep_kernel(const float* __restrict__ W1, const float* __restrict__ W2i,
                            const float* __restrict__ W2r, const float* __restrict__ W3,
                            unsigned short* __restrict__ wsu) {
    int i = blockIdx.x * 256 + threadIdx.x;          // 0..167935 exactly
    if (i < 131072) {
        int r = i & 65535;
        int j = r & 7, lane = (r >> 3) & 63, nt = (r >> 9) & 15, kt = r >> 13;
        int n = nt * 16 + (lane & 15);
        int k = kt * 32 + ((lane >> 4) << 3) + j;
        const float* W = (i < 65536) ? W2i : W2r;
        wsu[i] = f2bf(W[n * 256 + k]);
    } else if (i < 163840) {
        int r = i - 131072;
        int j = r & 7, lane = (r >> 3) & 63, nt = (r >> 9) & 15, kt = r >> 13;  // kt<4
        int n = nt * 16 + (lane & 15);
        int k = kt * 32 + ((lane >> 4) << 3) + j;
        wsu[i] = (k < CD_) ? f2bf(W1[n * CD_ + k]) : (unsigned short)0;
    } else {
        int r = i - 163840;                          // 0..4095
        int j = r & 7, lane = (r >> 3) & 63, kt = r >> 9;    // kt<8
        int o = lane & 15;
        int k = kt * 32 + ((lane >> 4) << 3) + j;
        wsu[i] = (o < OUT_) ? f2bf(W3[o * 256 + k]) : (unsigned short)0;
    }
}

// ---------------- full scan: 16 batch rows / block, MFMA everywhere ----------------
// LDS: 128K (W2in frags) + 3*8K (s1A/s2A/xsA) + 8K (W3 frags) = 163840 B exactly.
// W2rec frags live in 64 VGPRs/wave (16 frags); W3 frags moved regs->LDS to pay for it.
__global__ __launch_bounds__(512, 2) void scan_kernel(
    const float* __restrict__ x, const float* __restrict__ thr_p,
    const float* __restrict__ b1, const float* __restrict__ b2i,
    const float* __restrict__ b2r, const float* __restrict__ b3,
    const float* __restrict__ tau_adp1, const float* __restrict__ tau_m1,
    const float* __restrict__ tau_adp2, const float* __restrict__ tau_m2,
    const float* __restrict__ tau_m3,
    const unsigned short* __restrict__ wsu, float* __restrict__ out) {

    __shared__ __align__(16) unsigned short w2in_lds[65536];  // 128 KB, frag layout
    __shared__ __align__(16) unsigned short s1A[4096];        // A-frag layout [kt][lane][8]
    __shared__ __align__(16) unsigned short s2A[4096];
    __shared__ __align__(16) unsigned short xsA[4096];        // [t'][kt<4][lane][8]
    __shared__ __align__(16) unsigned short w3L[4096];        // W3 frags [kt<8][lane][8]

    const int tid  = threadIdx.x;
    const int wave = tid >> 6, lane = tid & 63;
    const int l15  = lane & 15, qd = lane >> 4;
    const int b0   = blockIdx.x * G_;
    const int nt0  = wave * 2, nt1 = nt0 + 1;

    // ---- prolog: W2in -> LDS; W3 -> LDS; zero s2A and xsA pad slots ----
    {
        const short8* src = (const short8*)(wsu + W2IN_F);
        short8* dst = (short8*)w2in_lds;
        #pragma unroll
        for (int i = 0; i < 16; ++i) dst[tid + i * 512] = src[tid + i * 512];
        ((short8*)w3L)[tid] = ((const short8*)(wsu + W3_F))[tid];   // 512*16B = 8KB
    }
    {
        short8 z = {0, 0, 0, 0, 0, 0, 0, 0};
        ((short8*)s2A)[tid] = z;                      // 512 * 16B = whole s2A
        if (tid >= 480) {                             // xsA (kt=3,q=3) zero pad, written once
            int idx = tid - 480, tp = idx >> 4, row = idx & 15;
            *(short8*)&xsA[((tp * 4 + 3) * 64 + 48 + row) * 8] = z;
        }
    }
    // persistent B-frags in regs: W1 (all waves), W2rec (all waves, 64 VGPRs)
    short8 w1b[2][4];
    #pragma unroll
    for (int i = 0; i < 2; ++i)
        #pragma unroll
        for (int kt = 0; kt < 4; ++kt)
            w1b[i][kt] = *(const short8*)&wsu[W1_F + ((kt * 16 + nt0 + i) * 64 + lane) * 8];
    short8 w2rb[2][8];
    #pragma unroll
    for (int i = 0; i < 2; ++i)
        #pragma unroll
        for (int kt = 0; kt < 8; ++kt)
            w2rb[i][kt] = *(const short8*)&wsu[W2REC_F + ((kt * 16 + nt0 + i) * 64 + lane) * 8];

    // per-column ALIF params (col = neuron n = nt*16 + l15)
    const float thrv = thr_p[0];
    float p_al1[2], p_rh1[2], p_b1[2], p_al2[2], p_rh2[2], p_b2[2];
    #pragma unroll
    for (int i = 0; i < 2; ++i) {
        int n = (nt0 + i) * 16 + l15;
        p_al1[i] = expf(-1.0f / tau_m1[n]);
        p_rh1[i] = expf(-1.0f / tau_adp1[n]);
        p_al2[i] = expf(-1.0f / tau_m2[n]);
        p_rh2[i] = expf(-1.0f / tau_adp2[n]);
        p_b1[i]  = b1[n];
        p_b2[i]  = b2i[n] + b2r[n];
    }
    const int oi = (l15 < OUT_) ? l15 : 0;
    const float p_al3 = expf(-1.0f / tau_m3[oi]);
    const float p_b3  = (l15 < OUT_) ? b3[l15] : 0.f;

    // x staging roles: threads 0..479 each own (t'=tid/240, row, k-octet)
    const bool stg = (tid < 480);
    int sc_t = 0, sc_off = 0;
    const float* px = x;
    if (stg) {
        sc_t = tid / 240; int srr = tid % 240;
        int row = srr / 15, oct = srr % 15, k0 = oct * 8;
        int c = k0 / D_, d = k0 % D_;
        px = x + ((size_t)(b0 + row) * C_ + c) * (size_t)(T_ * D_) + d;
        sc_off = ((sc_t * 4 + (k0 >> 5)) * 64 + ((k0 >> 3) & 3) * 16 + row) * 8;
    }

    float4 xr0 = {0,0,0,0}, xr1 = {0,0,0,0};
    if (stg) { const float* p = px + (size_t)sc_t * D_;          // tile 0
               xr0 = *(const float4*)p; xr1 = *(const float4*)(p + 4); }
    __syncthreads();                       // LDS copy/zero complete

    // stage tile 0
    if (stg) {
        float tf[8];
        *(float4*)&tf[0] = xr0; *(float4*)&tf[4] = xr1;
        __align__(16) unsigned short tu[8];
        #pragma unroll
        for (int j = 0; j < 8; ++j)
            tu[j] = ((tf[j] - thrv) > 0.f) ? (unsigned short)0x3F80
                  : (((-thrv - tf[j]) > 0.f) ? (unsigned short)0xBF80 : (unsigned short)0);
        *(short8*)&xsA[sc_off] = *(const short8*)tu;
    }
    __syncthreads();

    // i1 MFMA tile 0 -> i1c regs
    float i1c[2][2][4];
    #pragma unroll
    for (int tp = 0; tp < 2; ++tp) {
        f32x4 d0 = {0.f,0.f,0.f,0.f}, d1 = d0;
        #pragma unroll
        for (int kt = 0; kt < 4; ++kt) {
            short8 ax = *(const short8*)&xsA[((tp * 4 + kt) * 64 + lane) * 8];
            d0 = __builtin_amdgcn_mfma_f32_16x16x32_bf16(ax, w1b[0][kt], d0, 0, 0, 0);
            d1 = __builtin_amdgcn_mfma_f32_16x16x32_bf16(ax, w1b[1][kt], d1, 0, 0, 0);
        }
        #pragma unroll
        for (int r = 0; r < 4; ++r) { i1c[tp][0][r] = d0[r]; i1c[tp][1][r] = d1[r]; }
    }
    // prefetch tile 1 (global steps 2+sc_t)
    if (stg) { const float* p = px + (size_t)(2 + sc_t) * D_;
               xr0 = *(const float4*)p; xr1 = *(const float4*)(p + 4); }

    // recurrent state in C-layout regs: (row = qd*4+r, col = nt_i*16+l15)
    float m1s[8] = {0,0,0,0,0,0,0,0}, s1s[8] = {0,0,0,0,0,0,0,0}, a1s[8];
    float m2s[8] = {0,0,0,0,0,0,0,0}, s2s[8] = {0,0,0,0,0,0,0,0}, a2s[8];
    #pragma unroll
    for (int i = 0; i < 8; ++i) { a1s[i] = 0.01f; a2s[i] = 0.01f; }
    float m3v[4] = {0,0,0,0}, accv[4] = {0,0,0,0};
    float i2v[8];

    #pragma unroll 1
    for (int t = 0; t < T_; ++t) {
        // ---- P0: layer-1 ALIF + s1 -> A-frag layout in LDS ----
        {
            const int tp = t & 1;
            #pragma unroll
            for (int i = 0; i < 2; ++i) {
                const int nt = nt0 + i;
                const int koff = ((nt >> 1) * 64 + (((nt & 1) << 1) | (l15 >> 3)) * 16) * 8 + (l15 & 7);
                #pragma unroll
                for (int r = 0; r < 4; ++r) {
                    const int idx = i * 4 + r;
                    float I = p_b1[i] + i1c[tp][i][r];
                    a1s[idx] = p_rh1[i] * a1s[idx] + (1.f - p_rh1[i]) * s1s[idx];
                    float Bth = 0.01f + 1.8f * a1s[idx];
                    m1s[idx] = p_al1[i] * m1s[idx] + (1.f - p_al1[i]) * I - Bth * s1s[idx];
                    s1s[idx] = ((m1s[idx] - Bth) > 0.f) ? 1.f : 0.f;
                    s1A[koff + (qd * 4 + r) * 8] = (s1s[idx] > 0.5f) ? (unsigned short)0x3F80
                                                                     : (unsigned short)0;
                }
            }
        }
        __syncthreads();                                   // B1

        // ---- P1: i2 MFMA (W2in from LDS, W2rec from regs) + i3 (w7) + next-tile i1 (odd) ----
        {
            f32x4 c0a = {0.f,0.f,0.f,0.f}, c0b = c0a, c1a = c0a, c1b = c0a, c3 = c0a;
            __builtin_amdgcn_s_setprio(1);
            #pragma unroll
            for (int kt = 0; kt < 8; ++kt) {
                short8 a1f = *(const short8*)&s1A[(kt * 64 + lane) * 8];
                short8 a2f = *(const short8*)&s2A[(kt * 64 + lane) * 8];
                short8 bi0 = *(const short8*)&w2in_lds[((kt * 16 + nt0) * 64 + lane) * 8];
                short8 bi1 = *(const short8*)&w2in_lds[((kt * 16 + nt1) * 64 + lane) * 8];
                if (kt & 1) {
                    c0b = __builtin_amdgcn_mfma_f32_16x16x32_bf16(a1f, bi0, c0b, 0, 0, 0);
                    c1b = __builtin_amdgcn_mfma_f32_16x16x32_bf16(a1f, bi1, c1b, 0, 0, 0);
                    c0b = __builtin_amdgcn_mfma_f32_16x16x32_bf16(a2f, w2rb[0][kt], c0b, 0, 0, 0);
                    c1b = __builtin_amdgcn_mfma_f32_16x16x32_bf16(a2f, w2rb[1][kt], c1b, 0, 0, 0);
                } else {
                    c0a = __builtin_amdgcn_mfma_f32_16x16x32_bf16(a1f, bi0, c0a, 0, 0, 0);
                    c1a = __builtin_amdgcn_mfma_f32_16x16x32_bf16(a1f, bi1, c1a, 0, 0, 0);
                    c0a = __builtin_amdgcn_mfma_f32_16x16x32_bf16(a2f, w2rb[0][kt], c0a, 0, 0, 0);
                    c1a = __builtin_amdgcn_mfma_f32_16x16x32_bf16(a2f, w2rb[1][kt], c1a, 0, 0, 0);
                }
                if (wave == 7) {
                    short8 w3f = *(const short8*)&w3L[(kt * 64 + lane) * 8];
                    c3 = __builtin_amdgcn_mfma_f32_16x16x32_bf16(a2f, w3f, c3, 0, 0, 0);
                }
            }
            __builtin_amdgcn_s_setprio(0);
            #pragma unroll
            for (int r = 0; r < 4; ++r) { i2v[r] = c0a[r] + c0b[r]; i2v[4 + r] = c1a[r] + c1b[r]; }
            if (wave == 7 && t > 0) {                      // lagged layer-3 (step t-1)
                #pragma unroll
                for (int r = 0; r < 4; ++r) {
                    m3v[r] = p_al3 * m3v[r] + (1.f - p_al3) * (c3[r] + p_b3);
                    accv[r] += m3v[r];
                }
            }
            if ((t & 1) && t < T_ - 1) {                   // i1 for next tile
                #pragma unroll
                for (int tp = 0; tp < 2; ++tp) {
                    f32x4 d0 = {0.f,0.f,0.f,0.f}, d1 = d0;
                    #pragma unroll
                    for (int kt = 0; kt < 4; ++kt) {
                        short8 ax = *(const short8*)&xsA[((tp * 4 + kt) * 64 + lane) * 8];
                        d0 = __builtin_amdgcn_mfma_f32_16x16x32_bf16(ax, w1b[0][kt], d0, 0, 0, 0);
                        d1 = __builtin_amdgcn_mfma_f32_16x16x32_bf16(ax, w1b[1][kt], d1, 0, 0, 0);
                    }
                    #pragma unroll
                    for (int r = 0; r < 4; ++r) { i1c[tp][0][r] = d0[r]; i1c[tp][1][r] = d1[r]; }
                }
            }
        }
        __syncthreads();                                   // B2

        // ---- P2: layer-2 ALIF + s2 -> A-frag LDS; even t: stage next tile + prefetch ----
        // NOTE: no trailing barrier (old B3 removed). Hazards covered: P2 writes s2A/xsA are
        // separated from the NEXT iteration's P1 reads by B1; this iteration's P1 reads were
        // separated from these writes by B2. Next P0 touches only s1A (last written pre-B1,
        // last read pre-B2 of this iteration).
        {
            #pragma unroll
            for (int i = 0; i < 2; ++i) {
                const int nt = nt0 + i;
                const int koff = ((nt >> 1) * 64 + (((nt & 1) << 1) | (l15 >> 3)) * 16) * 8 + (l15 & 7);
                #pragma unroll
                for (int r = 0; r < 4; ++r) {
                    const int idx = i * 4 + r;
                    float I = p_b2[i] + i2v[idx];
                    a2s[idx] = p_rh2[i] * a2s[idx] + (1.f - p_rh2[i]) * s2s[idx];
                    float Bth = 0.01f + 1.8f * a2s[idx];
                    m2s[idx] = p_al2[i] * m2s[idx] + (1.f - p_al2[i]) * I - Bth * s2s[idx];
                    s2s[idx] = ((m2s[idx] - Bth) > 0.f) ? 1.f : 0.f;
                    s2A[koff + (qd * 4 + r) * 8] = (s2s[idx] > 0.5f) ? (unsigned short)0x3F80
                                                                     : (unsigned short)0;
                }
            }
            if (!(t & 1) && t < T_ - 2 && stg) {           // stage tile t/2+1 from regs
                float tf[8];
                *(float4*)&tf[0] = xr0; *(float4*)&tf[4] = xr1;
                __align__(16) unsigned short tu[8];
                #pragma unroll
                for (int j = 0; j < 8; ++j)
                    tu[j] = ((tf[j] - thrv) > 0.f) ? (unsigned short)0x3F80
                          : (((-thrv - tf[j]) > 0.f) ? (unsigned short)0xBF80 : (unsigned short)0);
                *(short8*)&xsA[sc_off] = *(const short8*)tu;
                if (t <= T_ - 6) {                         // prefetch global step t+4+sc_t
                    const float* p = px + (size_t)(t + 4 + sc_t) * D_;
                    xr0 = *(const float4*)p; xr1 = *(const float4*)(p + 4);
                }
            }
        }
    }
    __syncthreads();   // replaces old in-loop B3: s2A(T-1) writes -> flush reads below

    // ---- flush layer-3 for step T-1, then log_softmax + store (wave 7) ----
    if (wave == 7) {
        f32x4 c3 = {0.f,0.f,0.f,0.f};
        #pragma unroll
        for (int kt = 0; kt < 8; ++kt) {
            short8 a2f = *(const short8*)&s2A[(kt * 64 + lane) * 8];
            short8 w3f = *(const short8*)&w3L[(kt * 64 + lane) * 8];
            c3 = __builtin_amdgcn_mfma_f32_16x16x32_bf16(a2f, w3f, c3, 0, 0, 0);
        }
        #pragma unroll
        for (int r = 0; r < 4; ++r) {
            m3v[r] = p_al3 * m3v[r] + (1.f - p_al3) * (c3[r] + p_b3);
            accv[r] += m3v[r];
        }
        #pragma unroll
        for (int r = 0; r < 4; ++r) {
            float L = accv[r] / (float)T_;
            float mx = (l15 < OUT_) ? L : -1e30f;
            #pragma unroll
            for (int off = 1; off < 16; off <<= 1)
                mx = fmaxf(mx, __shfl_xor(mx, off, 16));
            float e = (l15 < OUT_) ? expf(L - mx) : 0.f;
            float se = e;
            #pragma unroll
            for (int off = 1; off < 16; off <<= 1)
                se += __shfl_xor(se, off, 16);
            if (l15 < OUT_)
                out[(size_t)(b0 + qd * 4 + r) * OUT_ + l15] = L - mx - logf(se);
        }
    }
}

// ---------------- host ----------------
extern "C" void kernel_launch(void* const* d_in, const int* in_sizes, int n_in,
                              void* d_out, int out_size, void* d_ws, size_t ws_size,
                              hipStream_t stream) {
    (void)in_sizes; (void)n_in; (void)out_size; (void)ws_size;
    const float* x        = (const float*)d_in[0];
    const float* thr      = (const float*)d_in[1];
    const float* W1       = (const float*)d_in[2];
    const float* b1       = (const float*)d_in[3];
    const float* W2_in    = (const float*)d_in[4];
    const float* b2_in    = (const float*)d_in[5];
    const float* W2_rec   = (const float*)d_in[6];
    const float* b2_rec   = (const float*)d_in[7];
    const float* W3       = (const float*)d_in[8];
    const float* b3       = (const float*)d_in[9];
    const float* tau_adp1 = (const float*)d_in[10];
    const float* tau_m1   = (const float*)d_in[11];
    const float* tau_adp2 = (const float*)d_in[12];
    const float* tau_m2   = (const float*)d_in[13];
    const float* tau_m3   = (const float*)d_in[14];
    unsigned short* wsu = (unsigned short*)d_ws;
    float* out = (float*)d_out;

    prep_kernel<<<656, 256, 0, stream>>>(W1, W2_in, W2_rec, W3, wsu);
    scan_kernel<<<B_ / G_, 512, 0, stream>>>(x, thr, b1, b2_in, b2_rec, b3,
                                             tau_adp1, tau_m1, tau_adp2, tau_m2,
                                             tau_m3, wsu, out);
}

// Round 4
// 1613.627 us; speedup vs baseline: 1.0035x; 1.0035x over previous
//
#include <hip/hip_runtime.h>
#include <math.h>

#define B_   512
#define T_   500
#define C_   3
#define D_   40
#define CD_  120
#define N_   256
#define OUT_ 12
#define G_   16          // batch rows per block -> 32 blocks

typedef __attribute__((ext_vector_type(8))) short short8;   // 8 x bf16 (4 VGPRs)
typedef __attribute__((ext_vector_type(4))) float f32x4;    // MFMA accumulator

// ws (ushort units): bf16 B-fragment tables.
// Frag layout (verified mapping): B[k][n], n = nt*16+(lane&15), k = kt*32+(lane>>4)*8+j
// element index = ((kt*16+nt)*64 + lane)*8 + j
#define W2IN_F  0        // kt<8, nt<16  -> 65536
#define W2REC_F 65536    // kt<8, nt<16  -> 65536
#define W1_F    131072   // kt<4, nt<16  -> 32768 (k>=120 zero)
#define W3_F    163840   // kt<8, single nt (cols=OUT pad 16) -> 4096

__device__ __forceinline__ unsigned short f2bf(float v) {
    unsigned x = __float_as_uint(v);
    unsigned r = (x + 0x7fffu + ((x >> 16) & 1u)) >> 16;   // round-nearest-even
    return (unsigned short)r;
}

// ---------------- prep: build bf16 B-fragment tables in ws ----------------
__global__ void prep_kernel(const float* __restrict__ W1, const float* __restrict__ W2i,
                            const float* __restrict__ W2r, const float* __restrict__ W3,
                            unsigned short* __restrict__ wsu) {
    int i = blockIdx.x * 256 + threadIdx.x;          // 0..167935 exactly
    if (i < 131072) {
        int r = i & 65535;
        int j = r & 7, lane = (r >> 3) & 63, nt = (r >> 9) & 15, kt = r >> 13;
        int n = nt * 16 + (lane & 15);
        int k = kt * 32 + ((lane >> 4) << 3) + j;
        const float* W = (i < 65536) ? W2i : W2r;
        wsu[i] = f2bf(W[n * 256 + k]);
    } else if (i < 163840) {
        int r = i - 131072;
        int j = r & 7, lane = (r >> 3) & 63, nt = (r >> 9) & 15, kt = r >> 13;  // kt<4
        int n = nt * 16 + (lane & 15);
        int k = kt * 32 + ((lane >> 4) << 3) + j;
        wsu[i] = (k < CD_) ? f2bf(W1[n * CD_ + k]) : (unsigned short)0;
    } else {
        int r = i - 163840;                          // 0..4095
        int j = r & 7, lane = (r >> 3) & 63, kt = r >> 9;    // kt<8
        int o = lane & 15;
        int k = kt * 32 + ((lane >> 4) << 3) + j;
        wsu[i] = (o < OUT_) ? f2bf(W3[o * 256 + k]) : (unsigned short)0;
    }
}

// ---------------- full scan: 16 batch rows / block, MFMA everywhere ----------------
// LDS: 128K (W2in frags) + 3*8K (s1A/s2A/xsA) + 8K (W3 frags) = 163840 B exactly.
// W2rec+W1 frags PINNED in VGPRs via asm (compiler rematerialized them at cap 128 —
// VGPR_Count=128 with no scratch traffic proved the loads were sunk into the loop).
// __launch_bounds__(512,1): 8-wave block forces <=256 VGPR anyway; only 32 blocks on
// 256 CUs so >1 block/CU occupancy is unreachable — don't cap registers for it.
__global__ __launch_bounds__(512, 1) void scan_kernel(
    const float* __restrict__ x, const float* __restrict__ thr_p,
    const float* __restrict__ b1, const float* __restrict__ b2i,
    const float* __restrict__ b2r, const float* __restrict__ b3,
    const float* __restrict__ tau_adp1, const float* __restrict__ tau_m1,
    const float* __restrict__ tau_adp2, const float* __restrict__ tau_m2,
    const float* __restrict__ tau_m3,
    const unsigned short* __restrict__ wsu, float* __restrict__ out) {

    __shared__ __align__(16) unsigned short w2in_lds[65536];  // 128 KB, frag layout
    __shared__ __align__(16) unsigned short s1A[4096];        // A-frag layout [kt][lane][8]
    __shared__ __align__(16) unsigned short s2A[4096];
    __shared__ __align__(16) unsigned short xsA[4096];        // [t'][kt<4][lane][8]
    __shared__ __align__(16) unsigned short w3L[4096];        // W3 frags [kt<8][lane][8]

    const int tid  = threadIdx.x;
    const int wave = tid >> 6, lane = tid & 63;
    const int l15  = lane & 15, qd = lane >> 4;
    const int b0   = blockIdx.x * G_;
    const int nt0  = wave * 2, nt1 = nt0 + 1;

    // ---- prolog: W2in -> LDS; W3 -> LDS; zero s2A and xsA pad slots ----
    {
        const short8* src = (const short8*)(wsu + W2IN_F);
        short8* dst = (short8*)w2in_lds;
        #pragma unroll
        for (int i = 0; i < 16; ++i) dst[tid + i * 512] = src[tid + i * 512];
        ((short8*)w3L)[tid] = ((const short8*)(wsu + W3_F))[tid];   // 512*16B = 8KB
    }
    {
        short8 z = {0, 0, 0, 0, 0, 0, 0, 0};
        ((short8*)s2A)[tid] = z;                      // 512 * 16B = whole s2A
        if (tid >= 480) {                             // xsA (kt=3,q=3) zero pad, written once
            int idx = tid - 480, tp = idx >> 4, row = idx & 15;
            *(short8*)&xsA[((tp * 4 + 3) * 64 + 48 + row) * 8] = z;
        }
    }
    // persistent B-frags in regs: W1 (all waves), W2rec (all waves, 64 VGPRs)
    short8 w1b[2][4];
    #pragma unroll
    for (int i = 0; i < 2; ++i)
        #pragma unroll
        for (int kt = 0; kt < 4; ++kt)
            w1b[i][kt] = *(const short8*)&wsu[W1_F + ((kt * 16 + nt0 + i) * 64 + lane) * 8];
    short8 w2rb[2][8];
    #pragma unroll
    for (int i = 0; i < 2; ++i)
        #pragma unroll
        for (int kt = 0; kt < 8; ++kt)
            w2rb[i][kt] = *(const short8*)&wsu[W2REC_F + ((kt * 16 + nt0 + i) * 64 + lane) * 8];
    // PIN the weight fragments: make them opaque so the compiler cannot sink the
    // loads back into the t-loop (rematerialization observed at VGPR cap 128).
    #pragma unroll
    for (int i = 0; i < 2; ++i) {
        #pragma unroll
        for (int kt = 0; kt < 4; ++kt) asm volatile("" : "+v"(w1b[i][kt]));
        #pragma unroll
        for (int kt = 0; kt < 8; ++kt) asm volatile("" : "+v"(w2rb[i][kt]));
    }

    // per-column ALIF params (col = neuron n = nt*16 + l15)
    const float thrv = thr_p[0];
    float p_al1[2], p_rh1[2], p_b1[2], p_al2[2], p_rh2[2], p_b2[2];
    #pragma unroll
    for (int i = 0; i < 2; ++i) {
        int n = (nt0 + i) * 16 + l15;
        p_al1[i] = expf(-1.0f / tau_m1[n]);
        p_rh1[i] = expf(-1.0f / tau_adp1[n]);
        p_al2[i] = expf(-1.0f / tau_m2[n]);
        p_rh2[i] = expf(-1.0f / tau_adp2[n]);
        p_b1[i]  = b1[n];
        p_b2[i]  = b2i[n] + b2r[n];
    }
    const int oi = (l15 < OUT_) ? l15 : 0;
    const float p_al3 = expf(-1.0f / tau_m3[oi]);
    const float p_b3  = (l15 < OUT_) ? b3[l15] : 0.f;

    // x staging roles: threads 0..479 each own (t'=tid/240, row, k-octet)
    const bool stg = (tid < 480);
    int sc_t = 0, sc_off = 0;
    const float* px = x;
    if (stg) {
        sc_t = tid / 240; int srr = tid % 240;
        int row = srr / 15, oct = srr % 15, k0 = oct * 8;
        int c = k0 / D_, d = k0 % D_;
        px = x + ((size_t)(b0 + row) * C_ + c) * (size_t)(T_ * D_) + d;
        sc_off = ((sc_t * 4 + (k0 >> 5)) * 64 + ((k0 >> 3) & 3) * 16 + row) * 8;
    }

    float4 xr0 = {0,0,0,0}, xr1 = {0,0,0,0};
    if (stg) { const float* p = px + (size_t)sc_t * D_;          // tile 0
               xr0 = *(const float4*)p; xr1 = *(const float4*)(p + 4); }
    __syncthreads();                       // LDS copy/zero complete

    // stage tile 0
    if (stg) {
        float tf[8];
        *(float4*)&tf[0] = xr0; *(float4*)&tf[4] = xr1;
        __align__(16) unsigned short tu[8];
        #pragma unroll
        for (int j = 0; j < 8; ++j)
            tu[j] = ((tf[j] - thrv) > 0.f) ? (unsigned short)0x3F80
                  : (((-thrv - tf[j]) > 0.f) ? (unsigned short)0xBF80 : (unsigned short)0);
        *(short8*)&xsA[sc_off] = *(const short8*)tu;
    }
    __syncthreads();

    // i1 MFMA tile 0 -> i1c regs
    float i1c[2][2][4];
    #pragma unroll
    for (int tp = 0; tp < 2; ++tp) {
        f32x4 d0 = {0.f,0.f,0.f,0.f}, d1 = d0;
        #pragma unroll
        for (int kt = 0; kt < 4; ++kt) {
            short8 ax = *(const short8*)&xsA[((tp * 4 + kt) * 64 + lane) * 8];
            d0 = __builtin_amdgcn_mfma_f32_16x16x32_bf16(ax, w1b[0][kt], d0, 0, 0, 0);
            d1 = __builtin_amdgcn_mfma_f32_16x16x32_bf16(ax, w1b[1][kt], d1, 0, 0, 0);
        }
        #pragma unroll
        for (int r = 0; r < 4; ++r) { i1c[tp][0][r] = d0[r]; i1c[tp][1][r] = d1[r]; }
    }
    // prefetch tile 1 (global steps 2+sc_t)
    if (stg) { const float* p = px + (size_t)(2 + sc_t) * D_;
               xr0 = *(const float4*)p; xr1 = *(const float4*)(p + 4); }

    // recurrent state in C-layout regs: (row = qd*4+r, col = nt_i*16+l15)
    float m1s[8] = {0,0,0,0,0,0,0,0}, s1s[8] = {0,0,0,0,0,0,0,0}, a1s[8];
    float m2s[8] = {0,0,0,0,0,0,0,0}, s2s[8] = {0,0,0,0,0,0,0,0}, a2s[8];
    #pragma unroll
    for (int i = 0; i < 8; ++i) { a1s[i] = 0.01f; a2s[i] = 0.01f; }
    float m3v[4] = {0,0,0,0}, accv[4] = {0,0,0,0};
    float i2v[8];

    #pragma unroll 1
    for (int t = 0; t < T_; ++t) {
        // ---- P0: layer-1 ALIF + s1 -> A-frag layout in LDS ----
        {
            const int tp = t & 1;
            #pragma unroll
            for (int i = 0; i < 2; ++i) {
                const int nt = nt0 + i;
                const int koff = ((nt >> 1) * 64 + (((nt & 1) << 1) | (l15 >> 3)) * 16) * 8 + (l15 & 7);
                #pragma unroll
                for (int r = 0; r < 4; ++r) {
                    const int idx = i * 4 + r;
                    float I = p_b1[i] + i1c[tp][i][r];
                    a1s[idx] = p_rh1[i] * a1s[idx] + (1.f - p_rh1[i]) * s1s[idx];
                    float Bth = 0.01f + 1.8f * a1s[idx];
                    m1s[idx] = p_al1[i] * m1s[idx] + (1.f - p_al1[i]) * I - Bth * s1s[idx];
                    s1s[idx] = ((m1s[idx] - Bth) > 0.f) ? 1.f : 0.f;
                    s1A[koff + (qd * 4 + r) * 8] = (s1s[idx] > 0.5f) ? (unsigned short)0x3F80
                                                                     : (unsigned short)0;
                }
            }
        }
        __syncthreads();                                   // B1

        // ---- P1: i2 MFMA (W2in from LDS, W2rec from regs) + i3 (w7) + next-tile i1 (odd) ----
        {
            f32x4 c0a = {0.f,0.f,0.f,0.f}, c0b = c0a, c1a = c0a, c1b = c0a, c3 = c0a;
            __builtin_amdgcn_s_setprio(1);
            #pragma unroll
            for (int kt = 0; kt < 8; ++kt) {
                short8 a1f = *(const short8*)&s1A[(kt * 64 + lane) * 8];
                short8 a2f = *(const short8*)&s2A[(kt * 64 + lane) * 8];
                short8 bi0 = *(const short8*)&w2in_lds[((kt * 16 + nt0) * 64 + lane) * 8];
                short8 bi1 = *(const short8*)&w2in_lds[((kt * 16 + nt1) * 64 + lane) * 8];
                if (kt & 1) {
                    c0b = __builtin_amdgcn_mfma_f32_16x16x32_bf16(a1f, bi0, c0b, 0, 0, 0);
                    c1b = __builtin_amdgcn_mfma_f32_16x16x32_bf16(a1f, bi1, c1b, 0, 0, 0);
                    c0b = __builtin_amdgcn_mfma_f32_16x16x32_bf16(a2f, w2rb[0][kt], c0b, 0, 0, 0);
                    c1b = __builtin_amdgcn_mfma_f32_16x16x32_bf16(a2f, w2rb[1][kt], c1b, 0, 0, 0);
                } else {
                    c0a = __builtin_amdgcn_mfma_f32_16x16x32_bf16(a1f, bi0, c0a, 0, 0, 0);
                    c1a = __builtin_amdgcn_mfma_f32_16x16x32_bf16(a1f, bi1, c1a, 0, 0, 0);
                    c0a = __builtin_amdgcn_mfma_f32_16x16x32_bf16(a2f, w2rb[0][kt], c0a, 0, 0, 0);
                    c1a = __builtin_amdgcn_mfma_f32_16x16x32_bf16(a2f, w2rb[1][kt], c1a, 0, 0, 0);
                }
                if (wave == 7) {
                    short8 w3f = *(const short8*)&w3L[(kt * 64 + lane) * 8];
                    c3 = __builtin_amdgcn_mfma_f32_16x16x32_bf16(a2f, w3f, c3, 0, 0, 0);
                }
            }
            __builtin_amdgcn_s_setprio(0);
            #pragma unroll
            for (int r = 0; r < 4; ++r) { i2v[r] = c0a[r] + c0b[r]; i2v[4 + r] = c1a[r] + c1b[r]; }
            if (wave == 7 && t > 0) {                      // lagged layer-3 (step t-1)
                #pragma unroll
                for (int r = 0; r < 4; ++r) {
                    m3v[r] = p_al3 * m3v[r] + (1.f - p_al3) * (c3[r] + p_b3);
                    accv[r] += m3v[r];
                }
            }
            if ((t & 1) && t < T_ - 1) {                   // i1 for next tile
                #pragma unroll
                for (int tp = 0; tp < 2; ++tp) {
                    f32x4 d0 = {0.f,0.f,0.f,0.f}, d1 = d0;
                    #pragma unroll
                    for (int kt = 0; kt < 4; ++kt) {
                        short8 ax = *(const short8*)&xsA[((tp * 4 + kt) * 64 + lane) * 8];
                        d0 = __builtin_amdgcn_mfma_f32_16x16x32_bf16(ax, w1b[0][kt], d0, 0, 0, 0);
                        d1 = __builtin_amdgcn_mfma_f32_16x16x32_bf16(ax, w1b[1][kt], d1, 0, 0, 0);
                    }
                    #pragma unroll
                    for (int r = 0; r < 4; ++r) { i1c[tp][0][r] = d0[r]; i1c[tp][1][r] = d1[r]; }
                }
            }
        }
        __syncthreads();                                   // B2

        // ---- P2: layer-2 ALIF + s2 -> A-frag LDS; even t: stage next tile + prefetch ----
        // NOTE: no trailing barrier (old B3 removed). Hazards covered: P2 writes s2A/xsA are
        // separated from the NEXT iteration's P1 reads by B1; this iteration's P1 reads were
        // separated from these writes by B2. Next P0 touches only s1A (last written pre-B1,
        // last read pre-B2 of this iteration).
        {
            #pragma unroll
            for (int i = 0; i < 2; ++i) {
                const int nt = nt0 + i;
                const int koff = ((nt >> 1) * 64 + (((nt & 1) << 1) | (l15 >> 3)) * 16) * 8 + (l15 & 7);
                #pragma unroll
                for (int r = 0; r < 4; ++r) {
                    const int idx = i * 4 + r;
                    float I = p_b2[i] + i2v[idx];
                    a2s[idx] = p_rh2[i] * a2s[idx] + (1.f - p_rh2[i]) * s2s[idx];
                    float Bth = 0.01f + 1.8f * a2s[idx];
                    m2s[idx] = p_al2[i] * m2s[idx] + (1.f - p_al2[i]) * I - Bth * s2s[idx];
                    s2s[idx] = ((m2s[idx] - Bth) > 0.f) ? 1.f : 0.f;
                    s2A[koff + (qd * 4 + r) * 8] = (s2s[idx] > 0.5f) ? (unsigned short)0x3F80
                                                                     : (unsigned short)0;
                }
            }
            if (!(t & 1) && t < T_ - 2 && stg) {           // stage tile t/2+1 from regs
                float tf[8];
                *(float4*)&tf[0] = xr0; *(float4*)&tf[4] = xr1;
                __align__(16) unsigned short tu[8];
                #pragma unroll
                for (int j = 0; j < 8; ++j)
                    tu[j] = ((tf[j] - thrv) > 0.f) ? (unsigned short)0x3F80
                          : (((-thrv - tf[j]) > 0.f) ? (unsigned short)0xBF80 : (unsigned short)0);
                *(short8*)&xsA[sc_off] = *(const short8*)tu;
                if (t <= T_ - 6) {                         // prefetch global step t+4+sc_t
                    const float* p = px + (size_t)(t + 4 + sc_t) * D_;
                    xr0 = *(const float4*)p; xr1 = *(const float4*)(p + 4);
                }
            }
        }
    }
    __syncthreads();   // replaces old in-loop B3: s2A(T-1) writes -> flush reads below

    // ---- flush layer-3 for step T-1, then log_softmax + store (wave 7) ----
    if (wave == 7) {
        f32x4 c3 = {0.f,0.f,0.f,0.f};
        #pragma unroll
        for (int kt = 0; kt < 8; ++kt) {
            short8 a2f = *(const short8*)&s2A[(kt * 64 + lane) * 8];
            short8 w3f = *(const short8*)&w3L[(kt * 64 + lane) * 8];
            c3 = __builtin_amdgcn_mfma_f32_16x16x32_bf16(a2f, w3f, c3, 0, 0, 0);
        }
        #pragma unroll
        for (int r = 0; r < 4; ++r) {
            m3v[r] = p_al3 * m3v[r] + (1.f - p_al3) * (c3[r] + p_b3);
            accv[r] += m3v[r];
        }
        #pragma unroll
        for (int r = 0; r < 4; ++r) {
            float L = accv[r] / (float)T_;
            float mx = (l15 < OUT_) ? L : -1e30f;
            #pragma unroll
            for (int off = 1; off < 16; off <<= 1)
                mx = fmaxf(mx, __shfl_xor(mx, off, 16));
            float e = (l15 < OUT_) ? expf(L - mx) : 0.f;
            float se = e;
            #pragma unroll
            for (int off = 1; off < 16; off <<= 1)
                se += __shfl_xor(se, off, 16);
            if (l15 < OUT_)
                out[(size_t)(b0 + qd * 4 + r) * OUT_ + l15] = L - mx - logf(se);
        }
    }
}

// ---------------- host ----------------
extern "C" void kernel_launch(void* const* d_in, const int* in_sizes, int n_in,
                              void* d_out, int out_size, void* d_ws, size_t ws_size,
                              hipStream_t stream) {
    (void)in_sizes; (void)n_in; (void)out_size; (void)ws_size;
    const float* x        = (const float*)d_in[0];
    const float* thr      = (const float*)d_in[1];
    const float* W1       = (const float*)d_in[2];
    const float* b1       = (const float*)d_in[3];
    const float* W2_in    = (const float*)d_in[4];
    const float* b2_in    = (const float*)d_in[5];
    const float* W2_rec   = (const float*)d_in[6];
    const float* b2_rec   = (const float*)d_in[7];
    const float* W3       = (const float*)d_in[8];
    const float* b3       = (const float*)d_in[9];
    const float* tau_adp1 = (const float*)d_in[10];
    const float* tau_m1   = (const float*)d_in[11];
    const float* tau_adp2 = (const float*)d_in[12];
    const float* tau_m2   = (const float*)d_in[13];
    const float* tau_m3   = (const float*)d_in[14];
    unsigned short* wsu = (unsigned short*)d_ws;
    float* out = (float*)d_out;

    prep_kernel<<<656, 256, 0, stream>>>(W1, W2_in, W2_rec, W3, wsu);
    scan_kernel<<<B_ / G_, 512, 0, stream>>>(x, thr, b1, b2_in, b2_rec, b3,
                                             tau_adp1, tau_m1, tau_adp2, tau_m2,
                                             tau_m3, wsu, out);
}